// Round 5
// baseline (1860.111 us; speedup 1.0000x reference)
//
#include <hip/hip_runtime.h>

// SentimentLSTM: B=64, T=512, E=128, H=256, V=100000, O=1
// outputs: sig_out[64], hT[1,64,256], cT[1,64,256] -> 32832 f32
//
// k_rec: 4 blocks = 2 group-pairs x 2 halves.
//   block (gpair, half): groups {2gp, 2gp+1} (16 batches each), units
//   half*128..+127, all 4 gates. W slice (512 rows x 256) bf16 = 128 VGPRs,
//   SHARED by both groups. Group B's compute hides group A's exchange RT.
//   Output head (dot with weff + sigmoid + mean) fused in after the poll.
//
// ws layout:
//   gx3  bf16 [T][8 slot][8 w][64 lane][16]  67,108,864 B  (lane-major)
//   hx   u64  [2 par][8 slot][1024]             131,072 B
//   weff f32  [257]                               1,028 B

#define BATCH 64
#define TSTEPS 512
#define EDIM 128
#define HDIM 256
#define G4H 1024

typedef short bf16x8 __attribute__((ext_vector_type(8)));
typedef short bf16x4 __attribute__((ext_vector_type(4)));
typedef float f32x4 __attribute__((ext_vector_type(4)));

__device__ __forceinline__ unsigned short f2bf(float f) {
  unsigned u = __builtin_bit_cast(unsigned, f);
  return (unsigned short)((u + 0x7fffu + ((u >> 16) & 1u)) >> 16);
}
__device__ __forceinline__ float bf2f(unsigned short h) {
  unsigned u = ((unsigned)h) << 16;
  return __builtin_bit_cast(float, u);
}
__device__ __forceinline__ unsigned pk2(float a, float b) {
  return (unsigned)f2bf(a) | ((unsigned)f2bf(b) << 16);
}
__device__ __forceinline__ float fsig(float x) {
  return __builtin_amdgcn_rcpf(1.f + __expf(-x));
}
__device__ __forceinline__ float ftanh(float x) {
  return 1.f - 2.f * __builtin_amdgcn_rcpf(__expf(2.f * x) + 1.f);
}
__device__ __forceinline__ bf16x8 ldfrag(const unsigned short* p) {
  bf16x4 a = *(const bf16x4*)p;
  bf16x4 b = *(const bf16x4*)(p + 16);
  return __builtin_shufflevector(a, b, 0, 1, 2, 3, 4, 5, 6, 7);
}

// ---------------- K1: gx3[lane-major layout] = emb[x] @ W_ih^T + b_ih ------
__global__ __launch_bounds__(256) void k_gx(const int* __restrict__ x,
                                            const float* __restrict__ emb,
                                            const float* __restrict__ Wih,
                                            const float* __restrict__ bih,
                                            unsigned short* __restrict__ gx3) {
  const int t = blockIdx.x;
  const int g0 = blockIdx.y * 64;
  const int tid = threadIdx.x;
  __shared__ unsigned short Al[64 * 136];
  __shared__ unsigned short Bl[64 * 136];
  __shared__ int tok[64];
  if (tid < 64) tok[tid] = x[tid * TSTEPS + t];
  __syncthreads();
  {
    const int r = tid >> 2, c0 = (tid & 3) * 32;
    const float* asrc = emb + (size_t)tok[r] * EDIM + c0;
    const float* bsrc = Wih + (size_t)(g0 + r) * EDIM + c0;
#pragma unroll
    for (int s = 0; s < 32; s += 8) {
      float4 a0 = *(const float4*)(asrc + s);
      float4 a1 = *(const float4*)(asrc + s + 4);
      uint4 pa = {pk2(a0.x, a0.y), pk2(a0.z, a0.w), pk2(a1.x, a1.y), pk2(a1.z, a1.w)};
      *(uint4*)&Al[r * 136 + c0 + s] = pa;
      float4 b0 = *(const float4*)(bsrc + s);
      float4 b1 = *(const float4*)(bsrc + s + 4);
      uint4 pb = {pk2(b0.x, b0.y), pk2(b0.z, b0.w), pk2(b1.x, b1.y), pk2(b1.z, b1.w)};
      *(uint4*)&Bl[r * 136 + c0 + s] = pb;
    }
  }
  __syncthreads();
  const int lane = tid & 63, w = tid >> 6;
  const int lo = lane & 15, hi = lane >> 4;
  const int mb = (w & 1) * 32, nb = (w >> 1) * 32;
  f32x4 acc[2][2];
#pragma unroll
  for (int jj = 0; jj < 2; ++jj) {
    float bv = bih[g0 + nb + jj * 16 + lo];
    acc[0][jj] = (f32x4){bv, bv, bv, bv};
    acc[1][jj] = acc[0][jj];
  }
#pragma unroll
  for (int kk = 0; kk < 4; ++kk) {
    bf16x8 af0 = ldfrag(&Al[(mb + lo) * 136 + kk * 32 + hi * 4]);
    bf16x8 af1 = ldfrag(&Al[(mb + 16 + lo) * 136 + kk * 32 + hi * 4]);
    bf16x8 bf0 = ldfrag(&Bl[(nb + lo) * 136 + kk * 32 + hi * 4]);
    bf16x8 bf1 = ldfrag(&Bl[(nb + 16 + lo) * 136 + kk * 32 + hi * 4]);
    acc[0][0] = __builtin_amdgcn_mfma_f32_16x16x32_bf16(af0, bf0, acc[0][0], 0, 0, 0);
    acc[0][1] = __builtin_amdgcn_mfma_f32_16x16x32_bf16(af0, bf1, acc[0][1], 0, 0, 0);
    acc[1][0] = __builtin_amdgcn_mfma_f32_16x16x32_bf16(af1, bf0, acc[1][0], 0, 0, 0);
    acc[1][1] = __builtin_amdgcn_mfma_f32_16x16x32_bf16(af1, bf1, acc[1][1], 0, 0, 0);
  }
  // packed u64 stores: 4 contiguous bf16 (g*4 + r, r=0..3) per (i,jj)
#pragma unroll
  for (int i = 0; i < 2; ++i)
#pragma unroll
    for (int jj = 0; jj < 2; ++jj) {
      int grp = (w & 1) * 2 + i;              // batch group (m>>4)
      int col = g0 + nb + jj * 16 + lo;
      int g = col >> 8, jc = col & 255;
      int halfb = jc >> 7, wv = (jc >> 4) & 7, lov = jc & 15;
      size_t base = (((size_t)(t * 8 + grp * 2 + halfb) * 8 + wv) * 64 +
                     (hi * 16 + lov)) * 16 + g * 4;
      unsigned long long val =
          (unsigned long long)pk2(acc[i][jj][0], acc[i][jj][1]) |
          ((unsigned long long)pk2(acc[i][jj][2], acc[i][jj][3]) << 32);
      *(unsigned long long*)&gx3[base] = val;
    }
}

// ---------------- K2: recurrence + fused output head -----------------------
__global__ __launch_bounds__(512, 2) void k_rec(const unsigned short* __restrict__ gx3,
                                                const float* __restrict__ Whh,
                                                const float* __restrict__ bhh,
                                                const float* __restrict__ weff,
                                                unsigned long long* __restrict__ hx,
                                                float* __restrict__ out) {
  const int tid = threadIdx.x;
  const int bp = blockIdx.x;                 // 0..3
  const int gpair = bp >> 1, half = bp & 1;
  const int gA = gpair * 2, gB = gpair * 2 + 1;
  const int lane = tid & 63, w = tid >> 6;
  const int lo = lane & 15, hi = lane >> 4;
  const int j = half * 128 + w * 16 + lo;    // this lane's unit (0..255)
  // h_lds[group][par]: k-major [granule=k>>3][batch][8 elems]
  __shared__ unsigned short h_lds[2][2][32 * 136];
  // persistent W: wf[g][kk][e] = Whh[g*256+j][kk*32 + hi*8 + e]  (bf16)
  bf16x8 wf[4][8];
  float bhv[4];
#pragma unroll
  for (int g = 0; g < 4; ++g) {
    const float* wr = Whh + (size_t)(g * 256 + j) * HDIM;
    bhv[g] = bhh[g * 256 + j];
#pragma unroll
    for (int kk = 0; kk < 8; ++kk) {
      const float* p = wr + kk * 32 + hi * 8;
      float4 v0 = *(const float4*)p;
      float4 v1 = *(const float4*)(p + 4);
      bf16x8 f;
      f[0] = (short)f2bf(v0.x); f[1] = (short)f2bf(v0.y);
      f[2] = (short)f2bf(v0.z); f[3] = (short)f2bf(v0.w);
      f[4] = (short)f2bf(v1.x); f[5] = (short)f2bf(v1.y);
      f[6] = (short)f2bf(v1.z); f[7] = (short)f2bf(v1.w);
      wf[g][kk] = f;
    }
  }
  // weff fragment for the fused head
  float wv8[8];
  {
    const float* wp = weff + (lane & 31) * 8;
#pragma unroll
    for (int e = 0; e < 8; ++e) wv8[e] = wp[e];
  }
  const float c0 = weff[256];
  // zero h_lds[.][0]
  for (int i = tid; i < 2 * 32 * 136 / 2; i += 512) {
    ((unsigned*)h_lds[0][0])[i & (32 * 136 / 2 - 1)] = 0u;  // group A buf0
    ((unsigned*)h_lds[1][0])[i & (32 * 136 / 2 - 1)] = 0u;  // group B buf0
  }
  // gx bases (slot = g*2+half), per-t stride = 65536 u16
  const unsigned short* gpA = gx3 + (((size_t)(gA * 2 + half) * 8 + w) * 64 + lane) * 16;
  const unsigned short* gpB = gx3 + (((size_t)(gB * 2 + half) * 8 + w) * 64 + lane) * 16;
  unsigned gwA[8], gwB[8];
  {
    uint4 a = *(const uint4*)(gpA);
    uint4 b = *(const uint4*)(gpA + 8);
    gwA[0] = a.x; gwA[1] = a.y; gwA[2] = a.z; gwA[3] = a.w;
    gwA[4] = b.x; gwA[5] = b.y; gwA[6] = b.z; gwA[7] = b.w;
    uint4 c = *(const uint4*)(gpB);
    uint4 d = *(const uint4*)(gpB + 8);
    gwB[0] = c.x; gwB[1] = c.y; gwB[2] = c.z; gwB[3] = c.w;
    gwB[4] = d.x; gwB[5] = d.y; gwB[6] = d.z; gwB[7] = d.w;
  }
  float cA[4] = {0.f, 0.f, 0.f, 0.f}, cB[4] = {0.f, 0.f, 0.f, 0.f};
  float hvA[4], hvB[4];
  float sig_acc = 0.f;
  const int ob = (j >> 3) * 136 + (j & 7);   // own-unit LDS offset
  const int jp = ((half ^ 1) * 128) + ((tid >> 6) << 4) + (tid & 15);
  const int hip = (tid >> 4) & 3;
  const int pb = (jp >> 3) * 136 + (jp & 7); // partner-unit LDS offset
  const int sA = gA * 2 + half, sB = gB * 2 + half;  // exchange slots
  __syncthreads();
  for (int t = 0; t < TSTEPS; ++t) {
    const int cur = t & 1, nxt = cur ^ 1;
    // prefetch gx(t+1) for both groups
    uint4 pA0, pA1, pB0, pB1;
    if (t < TSTEPS - 1) {
      const unsigned short* qA = gpA + (size_t)(t + 1) * 65536;
      const unsigned short* qB = gpB + (size_t)(t + 1) * 65536;
      pA0 = *(const uint4*)(qA);
      pA1 = *(const uint4*)(qA + 8);
      pB0 = *(const uint4*)(qB);
      pB1 = *(const uint4*)(qB + 8);
    }
    // C-init + MFMA, group A then group B (independent chains)
    f32x4 accA[4], accB[4];
#pragma unroll
    for (int g = 0; g < 4; ++g)
#pragma unroll
      for (int r = 0; r < 4; ++r) {
        unsigned wa = gwA[g * 2 + (r >> 1)];
        unsigned wb = gwB[g * 2 + (r >> 1)];
        unsigned short va = (r & 1) ? (unsigned short)(wa >> 16) : (unsigned short)wa;
        unsigned short vb = (r & 1) ? (unsigned short)(wb >> 16) : (unsigned short)wb;
        accA[g][r] = bf2f(va) + bhv[g];
        accB[g][r] = bf2f(vb) + bhv[g];
      }
#pragma unroll
    for (int kk = 0; kk < 8; ++kk) {
      bf16x8 a = *(const bf16x8*)&h_lds[0][cur][(kk * 4 + hi) * 136 + lo * 8];
      accA[0] = __builtin_amdgcn_mfma_f32_16x16x32_bf16(a, wf[0][kk], accA[0], 0, 0, 0);
      accA[1] = __builtin_amdgcn_mfma_f32_16x16x32_bf16(a, wf[1][kk], accA[1], 0, 0, 0);
      accA[2] = __builtin_amdgcn_mfma_f32_16x16x32_bf16(a, wf[2][kk], accA[2], 0, 0, 0);
      accA[3] = __builtin_amdgcn_mfma_f32_16x16x32_bf16(a, wf[3][kk], accA[3], 0, 0, 0);
    }
#pragma unroll
    for (int kk = 0; kk < 8; ++kk) {
      bf16x8 b = *(const bf16x8*)&h_lds[1][cur][(kk * 4 + hi) * 136 + lo * 8];
      accB[0] = __builtin_amdgcn_mfma_f32_16x16x32_bf16(b, wf[0][kk], accB[0], 0, 0, 0);
      accB[1] = __builtin_amdgcn_mfma_f32_16x16x32_bf16(b, wf[1][kk], accB[1], 0, 0, 0);
      accB[2] = __builtin_amdgcn_mfma_f32_16x16x32_bf16(b, wf[2][kk], accB[2], 0, 0, 0);
      accB[3] = __builtin_amdgcn_mfma_f32_16x16x32_bf16(b, wf[3][kk], accB[3], 0, 0, 0);
    }
    if (t < TSTEPS - 1) {
      gwA[0] = pA0.x; gwA[1] = pA0.y; gwA[2] = pA0.z; gwA[3] = pA0.w;
      gwA[4] = pA1.x; gwA[5] = pA1.y; gwA[6] = pA1.z; gwA[7] = pA1.w;
      gwB[0] = pB0.x; gwB[1] = pB0.y; gwB[2] = pB0.z; gwB[3] = pB0.w;
      gwB[4] = pB1.x; gwB[5] = pB1.y; gwB[6] = pB1.z; gwB[7] = pB1.w;
    }
    // lane-local cell updates
    unsigned short hbA[4], hbB[4];
#pragma unroll
    for (int r = 0; r < 4; ++r) {
      float iv = fsig(accA[0][r]), fv = fsig(accA[1][r]);
      float gv = ftanh(accA[2][r]), ov = fsig(accA[3][r]);
      cA[r] = fv * cA[r] + iv * gv;
      hvA[r] = ov * ftanh(cA[r]);
      hbA[r] = f2bf(hvA[r]);
    }
#pragma unroll
    for (int r = 0; r < 4; ++r) {
      float iv = fsig(accB[0][r]), fv = fsig(accB[1][r]);
      float gv = ftanh(accB[2][r]), ov = fsig(accB[3][r]);
      cB[r] = fv * cB[r] + iv * gv;
      hvB[r] = ov * ftanh(cB[r]);
      hbB[r] = f2bf(hvB[r]);
    }
    // tagged exchange stores (only vmem before the poll)
    const int par = (t + 1) & 1;
    const unsigned wt = (unsigned)(t + 1);
    {
      const unsigned long long tg = ((unsigned long long)wt) << 32;
      unsigned long long* dA = &hx[((size_t)(par * 8 + sA)) * 1024 + w * 128 + lane * 2];
      unsigned long long* dB = &hx[((size_t)(par * 8 + sB)) * 1024 + w * 128 + lane * 2];
      __hip_atomic_store(&dA[0], tg | (unsigned long long)pk2(hvA[0], hvA[1]),
                         __ATOMIC_RELAXED, __HIP_MEMORY_SCOPE_AGENT);
      __hip_atomic_store(&dA[1], tg | (unsigned long long)pk2(hvA[2], hvA[3]),
                         __ATOMIC_RELAXED, __HIP_MEMORY_SCOPE_AGENT);
      __hip_atomic_store(&dB[0], tg | (unsigned long long)pk2(hvB[0], hvB[1]),
                         __ATOMIC_RELAXED, __HIP_MEMORY_SCOPE_AGENT);
      __hip_atomic_store(&dB[1], tg | (unsigned long long)pk2(hvB[2], hvB[3]),
                         __ATOMIC_RELAXED, __HIP_MEMORY_SCOPE_AGENT);
    }
    // own halves into LDS (k-major)
#pragma unroll
    for (int r = 0; r < 4; ++r) {
      h_lds[0][nxt][ob + (hi * 4 + r) * 8] = hbA[r];
      h_lds[1][nxt][ob + (hi * 4 + r) * 8] = hbB[r];
    }
    // batched poll: 4 u64 per thread (2 per group), one quantization window
    {
      unsigned long long a0, a1, b0, b1;
      unsigned long long* qA = &hx[((size_t)(par * 8 + (sA ^ 1))) * 1024 + tid * 2];
      unsigned long long* qB = &hx[((size_t)(par * 8 + (sB ^ 1))) * 1024 + tid * 2];
      do {
        a0 = __hip_atomic_load(&qA[0], __ATOMIC_RELAXED, __HIP_MEMORY_SCOPE_AGENT);
        a1 = __hip_atomic_load(&qA[1], __ATOMIC_RELAXED, __HIP_MEMORY_SCOPE_AGENT);
        b0 = __hip_atomic_load(&qB[0], __ATOMIC_RELAXED, __HIP_MEMORY_SCOPE_AGENT);
        b1 = __hip_atomic_load(&qB[1], __ATOMIC_RELAXED, __HIP_MEMORY_SCOPE_AGENT);
      } while ((unsigned)(a0 >> 32) != wt || (unsigned)(a1 >> 32) != wt ||
               (unsigned)(b0 >> 32) != wt || (unsigned)(b1 >> 32) != wt);
      h_lds[0][nxt][pb + (hip * 4 + 0) * 8] = (unsigned short)a0;
      h_lds[0][nxt][pb + (hip * 4 + 1) * 8] = (unsigned short)(a0 >> 16);
      h_lds[0][nxt][pb + (hip * 4 + 2) * 8] = (unsigned short)a1;
      h_lds[0][nxt][pb + (hip * 4 + 3) * 8] = (unsigned short)(a1 >> 16);
      h_lds[1][nxt][pb + (hip * 4 + 0) * 8] = (unsigned short)b0;
      h_lds[1][nxt][pb + (hip * 4 + 1) * 8] = (unsigned short)(b0 >> 16);
      h_lds[1][nxt][pb + (hip * 4 + 2) * 8] = (unsigned short)b1;
      h_lds[1][nxt][pb + (hip * 4 + 3) * 8] = (unsigned short)(b1 >> 16);
    }
    __syncthreads();
    // fused output head: wave w dots 2 batches of group (w>>2) over full h_t
    {
      const int gsel = w >> 2;                       // 0 -> A, 1 -> B
      const int bb = half * 8 + (w & 3) * 2 + (lane >> 5);
      const int gran = lane & 31;
      bf16x8 hv8 = *(const bf16x8*)&h_lds[gsel][nxt][gran * 136 + bb * 8];
      float s = 0.f;
#pragma unroll
      for (int e = 0; e < 8; ++e) s += bf2f((unsigned short)hv8[e]) * wv8[e];
      s += __shfl_xor(s, 1);  s += __shfl_xor(s, 2);
      s += __shfl_xor(s, 4);  s += __shfl_xor(s, 8);
      s += __shfl_xor(s, 16);
      sig_acc += fsig(s + c0);
    }
  }
  // epilogue: hT, cT from registers; sig mean
#pragma unroll
  for (int r = 0; r < 4; ++r) {
    const int bA = gA * 16 + hi * 4 + r;
    const int bB = gB * 16 + hi * 4 + r;
    out[64 + bA * HDIM + j] = hvA[r];
    out[64 + BATCH * HDIM + bA * HDIM + j] = cA[r];
    out[64 + bB * HDIM + j] = hvB[r];
    out[64 + BATCH * HDIM + bB * HDIM + j] = cB[r];
  }
  if ((lane & 31) == 0) {
    const int gsel = w >> 2;
    const int bb = half * 8 + (w & 3) * 2 + (lane >> 5);
    const int b = (gpair * 2 + gsel) * 16 + bb;
    out[b] = sig_acc * (1.f / 512.f);
  }
}

// ---------------- K3: w_eff[k] = sum_j Wf[j]*Wm[j][k]; weff[256] = bm.Wf+bf --
__global__ __launch_bounds__(256) void k_weff(const float* __restrict__ Wm,
                                              const float* __restrict__ bm,
                                              const float* __restrict__ Wf,
                                              const float* __restrict__ bfb,
                                              float* __restrict__ weff) {
  const int k = threadIdx.x;
  __shared__ float red[256];
  float acc = 0.f;
#pragma unroll 8
  for (int jj = 0; jj < 256; ++jj) acc += Wf[jj] * Wm[jj * 256 + k];
  weff[k] = acc;
  red[k] = bm[k] * Wf[k];
  __syncthreads();
  for (int s = 128; s > 0; s >>= 1) {
    if (k < s) red[k] += red[k + s];
    __syncthreads();
  }
  if (k == 0) weff[256] = red[0] + bfb[0];
}

extern "C" void kernel_launch(void* const* d_in, const int* in_sizes, int n_in,
                              void* d_out, int out_size, void* d_ws, size_t ws_size,
                              hipStream_t stream) {
  (void)in_sizes; (void)n_in; (void)out_size; (void)ws_size;
  const int* x = (const int*)d_in[0];
  const float* emb = (const float*)d_in[1];
  const float* Wih = (const float*)d_in[2];
  const float* Whh = (const float*)d_in[3];
  const float* bih = (const float*)d_in[4];
  const float* bhh = (const float*)d_in[5];
  const float* Wm  = (const float*)d_in[6];
  const float* bm  = (const float*)d_in[7];
  const float* Wf  = (const float*)d_in[8];
  const float* bf  = (const float*)d_in[9];
  float* out = (float*)d_out;
  char* ws = (char*)d_ws;
  const size_t gx_bytes = (size_t)TSTEPS * BATCH * G4H * 2;  // 67,108,864
  const size_t hx_bytes = (size_t)2 * 8 * 1024 * 8;          // 131,072
  unsigned short* gx3 = (unsigned short*)ws;
  unsigned long long* hx = (unsigned long long*)(ws + gx_bytes);
  float* weff = (float*)(ws + gx_bytes + hx_bytes);
  hipMemsetAsync(hx, 0, hx_bytes, stream);  // tags start at 0 every launch
  k_gx<<<dim3(512, 16), 256, 0, stream>>>(x, emb, Wih, bih, gx3);
  k_weff<<<1, 256, 0, stream>>>(Wm, bm, Wf, bf, weff);
  k_rec<<<4, 512, 0, stream>>>(gx3, Whh, bhh, weff, hx, out);
}